// Round 9
// baseline (225.953 us; speedup 1.0000x reference)
//
#include <hip/hip_runtime.h>
#include <hip/hip_bf16.h>
#include <math.h>

// Problem: B=4, C=256, H=W=64 (N=4096), IC=128. I/O float32.
// R9: tail-kernel round. proj_k 3-way z-split (theta/phi/g separate blocks,
//     1536 blocks, 32KB LDS -> ~5 blk/CU), stats fused into wy_k (stats_k
//     removed). flash_k untouched from R8 (68 us).
typedef unsigned short ushort_t;
typedef __attribute__((ext_vector_type(8))) short     short8;   // bf16x8 MFMA frag
typedef __attribute__((ext_vector_type(8))) _Float16  half8;    // f16x8 MFMA frag
typedef __attribute__((ext_vector_type(8))) unsigned short ushort8;
typedef __attribute__((ext_vector_type(4))) float     float4v;

__device__ __forceinline__ float b2f(ushort_t u) {
    return __uint_as_float(((unsigned)u) << 16);
}
__device__ __forceinline__ ushort_t f2b(float f) {
    unsigned i = __float_as_uint(f);
    return (ushort_t)((i + 0x7FFFu + ((i >> 16) & 1u)) >> 16);  // RNE
}
__device__ __forceinline__ void split2(float v, ushort_t& h, ushort_t& l) {
    h = f2b(v);
    l = f2b(v - b2f(h));   // combined rel err ~2^-17
}
__device__ __forceinline__ void glds16(const ushort_t* g, ushort_t* l) {
    __builtin_amdgcn_global_load_lds((const __attribute__((address_space(1))) void*)g,
                                     (__attribute__((address_space(3))) void*)l, 16, 0, 0);
}

// ---- workspace layout (bytes) ----
#define WTFH_OFF   0            // 192 KB proj weights B-frag hi
#define WTFL_OFF   196608       // 192 KB lo
#define WWBH_OFF   393216       // 64 KB w_w bf16 hi
#define WWBL_OFF   458752       // 64 KB lo
#define BIAS_OFF   524288       // 384 f32
#define STATS_OFF  526336       // 512 f32
#define PROJF_OFF  1048576      // 8 MB fp16 (theta|phi) [b][n][256]
#define GT_OFF     9437184      // 4 MB bf16 g transposed [b][ic][n]
#define OPART_OFF  13631488     // KQ*8 MB f32 partial O; oml after
#define WY_OFF     1048576      // wy bf16 reuses PROJF region (dead after flash)

__global__ void prep_k(const float* __restrict__ dx_w, const float* __restrict__ dy_w,
                       const float* __restrict__ g_w,  const float* __restrict__ dx_b,
                       const float* __restrict__ dy_b, const float* __restrict__ g_b,
                       const float* __restrict__ w_w,
                       ushort_t* __restrict__ wtfh, ushort_t* __restrict__ wtfl,
                       ushort_t* __restrict__ wwbh, ushort_t* __restrict__ wwbl,
                       float* __restrict__ bias, float* __restrict__ stats) {
    int idx = blockIdx.x * 256 + threadIdx.x;          // 0..98303
    int j = idx & 7, lane = (idx >> 3) & 63, kk = (idx >> 9) & 7, ot = idx >> 12;
    int o = ot * 16 + (lane & 15);
    int c = kk * 32 + ((lane >> 4) * 8) + j;
    float v;
    if (o < 128)      v = dx_w[o * 256 + c];
    else if (o < 256) v = dy_w[(o - 128) * 256 + c];
    else              v = g_w[(o - 256) * 256 + c];
    ushort_t h, l;
    split2(v, h, l);
    wtfh[idx] = h; wtfl[idx] = l;
    if (idx < 32768) {                                 // w_w [256][128]
        split2(w_w[idx], h, l);
        wwbh[idx] = h; wwbl[idx] = l;
    }
    if (idx < 384) {
        bias[idx] = (idx < 128) ? dx_b[idx]
                  : (idx < 256) ? dy_b[idx - 128]
                                : g_b[idx - 256];
    }
    if (idx < 512) stats[idx] = 0.f;                   // ws 0xAA-poisoned each call
}

// ============================================================================
// Kernel 2: projections, z-split: z=0 theta(x), z=1 phi(y), z=2 g(y).
// 32-row n-tiles, 1536 blocks, 32KB LDS -> ~5 blk/CU. Split-bf16 compute;
// theta/phi stored fp16 (feeds fp16 S-phase), g stored bf16 into gT.
// 4 waves: (w&1) = 16-row half, (w>>1) = 4-ot half of this z's 8 ots.
// ============================================================================
__global__ __launch_bounds__(256) void proj_k(const float* __restrict__ x,
                                              const float* __restrict__ y,
                                              const ushort_t* __restrict__ wtfh,
                                              const ushort_t* __restrict__ wtfl,
                                              const float* __restrict__ bias,
                                              ushort_t* __restrict__ projf,
                                              ushort_t* __restrict__ gT) {
    __shared__ ushort_t xT[2][32 * 256];   // [hi/lo][n][c], 32KB
    int b = blockIdx.y, n0 = blockIdx.x * 32, z = blockIdx.z;
    int tid = threadIdx.x;
    int w = tid >> 6, lane = tid & 63;
    int mrow = lane & 15, quad = lane >> 4, koff = quad * 8;
    int half = w & 1, sect = w >> 1;
    int arow = half * 16 + mrow;
    const float* src = z ? y : x;

    #pragma unroll
    for (int i = 0; i < 4; i++) {
        int ch = tid + i * 256;               // 1024 chunks (32n x 256c / 8)
        int c = ch >> 2, off = (ch & 3) * 8;
        const float* p = src + (size_t)(b * 256 + c) * 4096 + n0 + off;
        float4v v0 = *(const float4v*)p;
        float4v v1 = *(const float4v*)(p + 4);
        #pragma unroll
        for (int jj = 0; jj < 4; jj++) {
            ushort_t h, l;
            split2(v0[jj], h, l);
            xT[0][(off + jj) * 256 + c] = h;
            xT[1][(off + jj) * 256 + c] = l;
            split2(v1[jj], h, l);
            xT[0][(off + 4 + jj) * 256 + c] = h;
            xT[1][(off + 4 + jj) * 256 + c] = l;
        }
    }
    __syncthreads();

    short8 fh[8], fl[8];
    #pragma unroll
    for (int kk = 0; kk < 8; kk++) {
        fh[kk] = *(const short8*)&xT[0][arow * 256 + kk * 32 + koff];
        fl[kk] = *(const short8*)&xT[1][arow * 256 + kk * 32 + koff];
    }

    int ot0 = z * 8 + sect * 4;
    for (int ot = ot0; ot < ot0 + 4; ot++) {
        float4v acc = {0.f, 0.f, 0.f, 0.f};
        #pragma unroll
        for (int kk = 0; kk < 8; kk++) {
            short8 bh = *(const short8*)(wtfh + (size_t)((ot * 8 + kk) * 64 + lane) * 8);
            short8 bl = *(const short8*)(wtfl + (size_t)((ot * 8 + kk) * 64 + lane) * 8);
            acc = __builtin_amdgcn_mfma_f32_16x16x32_bf16(fh[kk], bh, acc, 0, 0, 0);
            acc = __builtin_amdgcn_mfma_f32_16x16x32_bf16(fh[kk], bl, acc, 0, 0, 0);
            acc = __builtin_amdgcn_mfma_f32_16x16x32_bf16(fl[kk], bh, acc, 0, 0, 0);
        }
        int o = ot * 16 + mrow;                  // C/D: col = lane&15
        float bo = bias[o];
        #pragma unroll
        for (int r = 0; r < 4; r++) {
            int n = n0 + half * 16 + quad * 4 + r;  // C/D: row = quad*4 + reg
            float v = acc[r] + bo;
            if (z < 2) {
                _Float16 hf = (_Float16)v;
                projf[(size_t)(b * 4096 + n) * 256 + o] = *(ushort_t*)&hf;
            } else {
                gT[(size_t)(b * 128 + (o - 256)) * 4096 + n] = f2b(v);
            }
        }
    }
}

// ============================================================================
// Kernel 3 (unchanged from R8): flash, 512 threads (8 waves x 32 q-rows),
// K-split, double-buffered glds staging (1 barrier/iter), fp16 S-phase,
// fixed-shift softmax, l via ones-MFMA, Ps wave-private.
// ============================================================================
__global__ __launch_bounds__(512, 2) void flash_k(const ushort_t* __restrict__ projf,
                                                  const ushort_t* __restrict__ gT,
                                                  float* __restrict__ opart,
                                                  float* __restrict__ oml,
                                                  int kqlog) {
    __shared__ __align__(16) ushort_t KsF[2][8192];  // fp16 K, frag-order
    __shared__ __align__(16) ushort_t VsF[2][8192];  // bf16 V, frag-order
    __shared__ __align__(16) ushort_t Ps[256 * 72];  // [qrow][key], wave-private rows

    int b = blockIdx.y;
    int kq = blockIdx.x & ((1 << kqlog) - 1);
    int q0 = (blockIdx.x >> kqlog) * 256;
    int iters = 64 >> kqlog;
    int kt0 = kq * iters;
    int tid = threadIdx.x, w = tid >> 6, lane = tid & 63;
    int mrow = lane & 15, quad = lane >> 4, koff = quad * 8;

    int kRow[2], kCol[2], vIc[2], vOf[2], dstB[2];
    #pragma unroll
    for (int i = 0; i < 2; i++) {
        int ck = tid + i * 512, combo = ck >> 6, l2 = ck & 63;
        kRow[i] = (combo >> 2) * 16 + (l2 & 15);
        kCol[i] = 128 + (combo & 3) * 32 + (l2 >> 4) * 8;
        vIc[i]  = (combo >> 1) * 16 + (l2 & 15);
        vOf[i]  = (combo & 1) * 32 + (l2 >> 4) * 8;
        dstB[i] = (i * 512 + w * 64) * 8;
    }

    half8 qf[2][4];
    #pragma unroll
    for (int s = 0; s < 2; s++)
        #pragma unroll
        for (int kk = 0; kk < 4; kk++)
            qf[s][kk] = *(const half8*)(projf + (size_t)(b * 4096 + q0 + w * 32 + s * 16 + mrow) * 256
                                        + kk * 32 + koff);

    float4v oacc[2][8], oaccL[2];
    #pragma unroll
    for (int s = 0; s < 2; s++) {
        oaccL[s] = (float4v){0.f, 0.f, 0.f, 0.f};
        #pragma unroll
        for (int ot = 0; ot < 8; ot++) oacc[s][ot] = (float4v){0.f, 0.f, 0.f, 0.f};
    }
    short8 vones;
    #pragma unroll
    for (int j = 0; j < 8; j++) vones[j] = (short)0x3F80;  // bf16 1.0

    {
        int kb = kt0 * 64;
        #pragma unroll
        for (int i = 0; i < 2; i++) {
            glds16(projf + (size_t)(b * 4096 + kb + kRow[i]) * 256 + kCol[i], &KsF[0][dstB[i]]);
            glds16(gT + (size_t)(b * 128 + vIc[i]) * 4096 + kb + vOf[i], &VsF[0][dstB[i]]);
        }
    }

    for (int kt = kt0; kt < kt0 + iters; kt++) {
        int cur = (kt - kt0) & 1;
        __syncthreads();                             // publishes buf[cur] (vmcnt drain)
        if (kt + 1 < kt0 + iters) {
            int kb = (kt + 1) * 64;
            #pragma unroll
            for (int i = 0; i < 2; i++) {
                glds16(projf + (size_t)(b * 4096 + kb + kRow[i]) * 256 + kCol[i], &KsF[1 - cur][dstB[i]]);
                glds16(gT + (size_t)(b * 128 + vIc[i]) * 4096 + kb + vOf[i], &VsF[1 - cur][dstB[i]]);
            }
        }

        float4v sacc[2][4];
        #pragma unroll
        for (int ct = 0; ct < 4; ct++) {
            float4v a0 = {0.f, 0.f, 0.f, 0.f}, a1 = {0.f, 0.f, 0.f, 0.f};
            #pragma unroll
            for (int kk = 0; kk < 4; kk++) {
                half8 bh = *(const half8*)&KsF[cur][((ct * 4 + kk) * 64 + lane) * 8];
                a0 = __builtin_amdgcn_mfma_f32_16x16x32_f16(qf[0][kk], bh, a0, 0, 0, 0);
                a1 = __builtin_amdgcn_mfma_f32_16x16x32_f16(qf[1][kk], bh, a1, 0, 0, 0);
            }
            sacc[0][ct] = a0; sacc[1][ct] = a1;
        }

        #pragma unroll
        for (int s = 0; s < 2; s++)
            #pragma unroll
            for (int r = 0; r < 4; r++) {
                int prow = w * 32 + s * 16 + quad * 4 + r;
                #pragma unroll
                for (int ct = 0; ct < 4; ct++) {
                    float p = __builtin_exp2f(fmaf(sacc[s][ct][r], 1.44269504f, -92.332481f));
                    Ps[prow * 72 + ct * 16 + mrow] = f2b(p);
                }
            }
        __builtin_amdgcn_s_waitcnt(0xC07F);          // lgkmcnt(0): wave-private Ps

        #pragma unroll
        for (int k2 = 0; k2 < 2; k2++) {
            short8 a0 = *(const short8*)&Ps[(w * 32 + mrow) * 72 + k2 * 32 + koff];
            short8 a1 = *(const short8*)&Ps[(w * 32 + 16 + mrow) * 72 + k2 * 32 + koff];
            #pragma unroll
            for (int ot = 0; ot < 8; ot++) {
                short8 bfr = *(const short8*)&VsF[cur][((ot * 2 + k2) * 64 + lane) * 8];
                oacc[0][ot] = __builtin_amdgcn_mfma_f32_16x16x32_bf16(a0, bfr, oacc[0][ot], 0, 0, 0);
                oacc[1][ot] = __builtin_amdgcn_mfma_f32_16x16x32_bf16(a1, bfr, oacc[1][ot], 0, 0, 0);
            }
            oaccL[0] = __builtin_amdgcn_mfma_f32_16x16x32_bf16(a0, vones, oaccL[0], 0, 0, 0);
            oaccL[1] = __builtin_amdgcn_mfma_f32_16x16x32_bf16(a1, vones, oaccL[1], 0, 0, 0);
        }
    }

    #pragma unroll
    for (int s = 0; s < 2; s++)
        #pragma unroll
        for (int ot = 0; ot < 8; ot++)
            #pragma unroll
            for (int r = 0; r < 4; r++) {
                int R = b * 4096 + q0 + w * 32 + s * 16 + quad * 4 + r;
                opart[((size_t)kq * 16384 + R) * 128 + ot * 16 + mrow] = oacc[s][ot][r];
            }
    if (mrow == 0) {
        #pragma unroll
        for (int s = 0; s < 2; s++)
            #pragma unroll
            for (int r = 0; r < 4; r++) {
                int R = b * 4096 + q0 + w * 32 + s * 16 + quad * 4 + r;
                oml[kq * 16384 + R] = oaccL[s][r];
            }
    }
}

// ============================================================================
// Kernel 4: wy = w_w . y2^T + w_b with inline merge of KQ partials + fused
// per-channel sum/sumsq (shuffle-reduce -> LDS -> global atomics).
// ============================================================================
__global__ __launch_bounds__(256) void wy_k(const float* __restrict__ opart,
                                            const float* __restrict__ oml,
                                            const ushort_t* __restrict__ wwbh,
                                            const ushort_t* __restrict__ wwbl,
                                            const float* __restrict__ w_b,
                                            ushort_t* __restrict__ wy,
                                            float* __restrict__ stats, int KQ) {
    __shared__ float s_sum[256], s_sq[256];
    int b = blockIdx.y, n0 = blockIdx.x * 32;
    int tid = threadIdx.x, w = tid >> 6, lane = tid & 63;
    s_sum[tid] = 0.f; s_sq[tid] = 0.f;
    __syncthreads();
    int mrow = lane & 15, quad = lane >> 4, koff = quad * 8;
    int half = w & 1, sect = w >> 1;
    int Rn = b * 4096 + n0 + half * 16 + mrow;

    float L = 0.f;
    for (int kq = 0; kq < KQ; kq++) L += oml[kq * 16384 + Rn];
    float invL = 1.f / L;

    short8 bfh[4], bfl[4];
    #pragma unroll
    for (int kk = 0; kk < 4; kk++) {
        float a[8];
        #pragma unroll
        for (int j = 0; j < 8; j++) a[j] = 0.f;
        for (int kq = 0; kq < KQ; kq++) {
            const float* p = opart + ((size_t)kq * 16384 + Rn) * 128 + kk * 32 + koff;
            float4v v0 = *(const float4v*)p;
            float4v v1 = *(const float4v*)(p + 4);
            #pragma unroll
            for (int j = 0; j < 4; j++) { a[j] += v0[j]; a[4 + j] += v1[j]; }
        }
        #pragma unroll
        for (int j = 0; j < 8; j++) {
            ushort_t h, l;
            split2(a[j] * invL, h, l);
            bfh[kk][j] = (short)h; bfl[kk][j] = (short)l;
        }
    }

    int coln = n0 + half * 16 + mrow;
    for (int cot = sect * 8; cot < sect * 8 + 8; cot++) {
        float4v acc = {0.f, 0.f, 0.f, 0.f};
        #pragma unroll
        for (int kk = 0; kk < 4; kk++) {
            size_t woff = (size_t)(cot * 16 + mrow) * 128 + kk * 32 + koff;
            short8 ah = *(const short8*)(wwbh + woff);
            short8 al = *(const short8*)(wwbl + woff);
            acc = __builtin_amdgcn_mfma_f32_16x16x32_bf16(ah, bfh[kk], acc, 0, 0, 0);
            acc = __builtin_amdgcn_mfma_f32_16x16x32_bf16(ah, bfl[kk], acc, 0, 0, 0);
            acc = __builtin_amdgcn_mfma_f32_16x16x32_bf16(al, bfh[kk], acc, 0, 0, 0);
        }
        #pragma unroll
        for (int r = 0; r < 4; r++) {
            int co = cot * 16 + quad * 4 + r;
            float v = acc[r] + w_b[co];
            wy[(size_t)(b * 256 + co) * 4096 + coln] = f2b(v);
            float sv = v, sq = v * v;
            #pragma unroll
            for (int d = 1; d < 16; d <<= 1) {
                sv += __shfl_xor(sv, d, 64);
                sq += __shfl_xor(sq, d, 64);
            }
            if (mrow == 0) { atomicAdd(&s_sum[co], sv); atomicAdd(&s_sq[co], sq); }
        }
    }
    __syncthreads();
    atomicAdd(&stats[tid], s_sum[tid]);
    atomicAdd(&stats[256 + tid], s_sq[tid]);
}

// ============================================================================
// Kernel 5: BN (batch stats, biased var, eps=1e-5) + residual, f32 out.
// ============================================================================
__global__ __launch_bounds__(256) void bn_k(const ushort_t* __restrict__ wy,
                                            const float* __restrict__ x,
                                            const float* __restrict__ gamma,
                                            const float* __restrict__ beta,
                                            const float* __restrict__ stats,
                                            float* __restrict__ out) {
    int idx = (blockIdx.x * 256 + threadIdx.x) * 8;     // B*C*N = 1<<22
    int c = (idx >> 12) & 255;
    const float inv_cnt = 1.f / 16384.f;
    float mean = stats[c] * inv_cnt;
    float var  = stats[256 + c] * inv_cnt - mean * mean;
    float inv  = rsqrtf(var + 1e-5f);
    float scale = gamma[c] * inv;
    float shift = beta[c] - mean * scale;
    ushort8 wv = *(const ushort8*)(wy + idx);
    float4v x0 = *(const float4v*)(x + idx);
    float4v x1 = *(const float4v*)(x + idx + 4);
    float4v o0, o1;
    #pragma unroll
    for (int j = 0; j < 4; j++) {
        o0[j] = b2f(wv[j]) * scale + shift + x0[j];
        o1[j] = b2f(wv[4 + j]) * scale + shift + x1[j];
    }
    *(float4v*)(out + idx) = o0;
    *(float4v*)(out + idx + 4) = o1;
}

extern "C" void kernel_launch(void* const* d_in, const int* in_sizes, int n_in,
                              void* d_out, int out_size, void* d_ws, size_t ws_size,
                              hipStream_t stream) {
    const float* x    = (const float*)d_in[0];
    const float* y    = (const float*)d_in[1];
    const float* g_w  = (const float*)d_in[2];
    const float* g_b  = (const float*)d_in[3];
    const float* dx_w = (const float*)d_in[4];
    const float* dx_b = (const float*)d_in[5];
    const float* dy_w = (const float*)d_in[6];
    const float* dy_b = (const float*)d_in[7];
    const float* w_w  = (const float*)d_in[8];
    const float* w_b  = (const float*)d_in[9];
    const float* bn_g = (const float*)d_in[10];
    const float* bn_b = (const float*)d_in[11];

    char* ws = (char*)d_ws;
    ushort_t* wtfh  = (ushort_t*)(ws + WTFH_OFF);
    ushort_t* wtfl  = (ushort_t*)(ws + WTFL_OFF);
    ushort_t* wwbh  = (ushort_t*)(ws + WWBH_OFF);
    ushort_t* wwbl  = (ushort_t*)(ws + WWBL_OFF);
    float*    bias  = (float*)(ws + BIAS_OFF);
    float*    stats = (float*)(ws + STATS_OFF);
    ushort_t* projf = (ushort_t*)(ws + PROJF_OFF);
    ushort_t* gT    = (ushort_t*)(ws + GT_OFF);
    float*    opart = (float*)(ws + OPART_OFF);
    ushort_t* wy    = (ushort_t*)(ws + WY_OFF);   // reuses projf region
    float*    out   = (float*)d_out;

    int kqlog;
    if      (ws_size >= 13631488u + 4u * (8388608u + 65536u)) kqlog = 2;
    else if (ws_size >= 13631488u + 2u * (8388608u + 65536u)) kqlog = 1;
    else                                                      kqlog = 0;
    int KQ = 1 << kqlog;
    float* oml = (float*)(ws + OPART_OFF + (size_t)KQ * 8388608u);

    prep_k<<<384, 256, 0, stream>>>(dx_w, dy_w, g_w, dx_b, dy_b, g_b, w_w,
                                    wtfh, wtfl, wwbh, wwbl, bias, stats);
    proj_k<<<dim3(128, 4, 3), 256, 0, stream>>>(x, y, wtfh, wtfl, bias, projf, gT);
    flash_k<<<dim3(16 << kqlog, 4), 512, 0, stream>>>(projf, gT, opart, oml, kqlog);
    wy_k<<<dim3(128, 4), 256, 0, stream>>>(opart, oml, wwbh, wwbl, w_b, wy, stats, KQ);
    bn_k<<<2048, 256, 0, stream>>>(wy, x, bn_g, bn_b, stats, out);
}

// Round 11
// 224.028 us; speedup vs baseline: 1.0086x; 1.0086x over previous
//
#include <hip/hip_runtime.h>
#include <hip/hip_bf16.h>
#include <math.h>

// Problem: B=4, C=256, H=W=64 (N=4096), IC=128. I/O float32.
// R11 (= R10 with workspace-overlap fix: wtf is 192 KB, not 96 KB — prep_k
// was clobbering wwbh/wwbl -> garbage weights -> inf/NaN).
// proj single-fp16 MFMA; flash S^T orientation, 4 q-strips/wave, packed Ps,
// KQ=8 bf16 partials; wy split-bf16.
typedef unsigned short ushort_t;
typedef __attribute__((ext_vector_type(8))) short     short8;   // bf16x8 frag
typedef __attribute__((ext_vector_type(8))) _Float16  half8;    // f16x8 frag
typedef __attribute__((ext_vector_type(8))) unsigned short ushort8;
typedef __attribute__((ext_vector_type(4))) unsigned short ushort4v;
typedef __attribute__((ext_vector_type(4))) float     float4v;

__device__ __forceinline__ float b2f(ushort_t u) {
    return __uint_as_float(((unsigned)u) << 16);
}
__device__ __forceinline__ ushort_t f2b(float f) {
    unsigned i = __float_as_uint(f);
    return (ushort_t)((i + 0x7FFFu + ((i >> 16) & 1u)) >> 16);  // RNE
}
__device__ __forceinline__ void split2(float v, ushort_t& h, ushort_t& l) {
    h = f2b(v);
    l = f2b(v - b2f(h));
}
__device__ __forceinline__ ushort_t f2h(float v) {
    _Float16 h = (_Float16)v;
    return *(ushort_t*)&h;
}
__device__ __forceinline__ void glds16(const ushort_t* g, ushort_t* l) {
    __builtin_amdgcn_global_load_lds((const __attribute__((address_space(1))) void*)g,
                                     (__attribute__((address_space(3))) void*)l, 16, 0, 0);
}

// ---- workspace layout (bytes) ----
#define WTF_OFF    0            // 98304 fp16 = 192 KB proj weights, B-frag order
#define WWBH_OFF   196608       // 64 KB w_w bf16 hi
#define WWBL_OFF   262144       // 64 KB lo
#define BIAS_OFF   327680       // 384 f32
#define STATS_OFF  329216       // 512 f32
#define PROJF_OFF  393216       // 8 MB fp16 (theta|phi) [b][n][256]
#define GT_OFF     8781824      // 4 MB bf16 g transposed [b][ic][n]
#define OPART_OFF  12976128     // KQ*4 MB bf16 partial O; oml (bf16) after
#define WY_OFF     393216       // wy bf16 (8 MB) reuses PROJF region
// KQ=8 end: 12976128 + 8*(4194304+32768) = 46792704 < known-good ws (>=47.4 MB)

__global__ void prep_k(const float* __restrict__ dx_w, const float* __restrict__ dy_w,
                       const float* __restrict__ g_w,  const float* __restrict__ dx_b,
                       const float* __restrict__ dy_b, const float* __restrict__ g_b,
                       const float* __restrict__ w_w,
                       ushort_t* __restrict__ wtf,
                       ushort_t* __restrict__ wwbh, ushort_t* __restrict__ wwbl,
                       float* __restrict__ bias, float* __restrict__ stats) {
    int idx = blockIdx.x * 256 + threadIdx.x;          // 0..98303
    int j = idx & 7, lane = (idx >> 3) & 63, kk = (idx >> 9) & 7, ot = idx >> 12;
    int o = ot * 16 + (lane & 15);
    int c = kk * 32 + ((lane >> 4) * 8) + j;
    float v;
    if (o < 128)      v = dx_w[o * 256 + c];
    else if (o < 256) v = dy_w[(o - 128) * 256 + c];
    else              v = g_w[(o - 256) * 256 + c];
    wtf[idx] = f2h(v);
    if (idx < 32768) {                                 // w_w [256][128]
        ushort_t h, l;
        split2(w_w[idx], h, l);
        wwbh[idx] = h; wwbl[idx] = l;
    }
    if (idx < 384) {
        bias[idx] = (idx < 128) ? dx_b[idx]
                  : (idx < 256) ? dy_b[idx - 128]
                                : g_b[idx - 256];
    }
    if (idx < 512) stats[idx] = 0.f;                   // ws poisoned each call
}

// ============================================================================
// Kernel 2: projections, fp16 single MFMA, z-split (z=0 theta(x), 1 phi(y),
// 2 g(y)), 32-row n-tiles.
// ============================================================================
__global__ __launch_bounds__(256) void proj_k(const float* __restrict__ x,
                                              const float* __restrict__ y,
                                              const ushort_t* __restrict__ wtf,
                                              const float* __restrict__ bias,
                                              ushort_t* __restrict__ projf,
                                              ushort_t* __restrict__ gT) {
    __shared__ ushort_t xT[32 * 256];      // fp16 [n][c], 16KB
    int b = blockIdx.y, n0 = blockIdx.x * 32, z = blockIdx.z;
    int tid = threadIdx.x;
    int w = tid >> 6, lane = tid & 63;
    int mrow = lane & 15, quad = lane >> 4, koff = quad * 8;
    int half = w & 1, sect = w >> 1;
    int arow = half * 16 + mrow;
    const float* src = z ? y : x;

    #pragma unroll
    for (int i = 0; i < 4; i++) {
        int ch = tid + i * 256;
        int c = ch >> 2, off = (ch & 3) * 8;
        const float* p = src + (size_t)(b * 256 + c) * 4096 + n0 + off;
        float4v v0 = *(const float4v*)p;
        float4v v1 = *(const float4v*)(p + 4);
        #pragma unroll
        for (int jj = 0; jj < 4; jj++) {
            xT[(off + jj) * 256 + c]     = f2h(v0[jj]);
            xT[(off + 4 + jj) * 256 + c] = f2h(v1[jj]);
        }
    }
    __syncthreads();

    half8 fx[8];
    #pragma unroll
    for (int kk = 0; kk < 8; kk++)
        fx[kk] = *(const half8*)&xT[arow * 256 + kk * 32 + koff];

    int ot0 = z * 8 + sect * 4;
    for (int ot = ot0; ot < ot0 + 4; ot++) {
        float4v acc = {0.f, 0.f, 0.f, 0.f};
        #pragma unroll
        for (int kk = 0; kk < 8; kk++) {
            half8 bfr = *(const half8*)(wtf + (size_t)((ot * 8 + kk) * 64 + lane) * 8);
            acc = __builtin_amdgcn_mfma_f32_16x16x32_f16(fx[kk], bfr, acc, 0, 0, 0);
        }
        int o = ot * 16 + mrow;                  // C/D: col = lane&15
        float bo = bias[o];
        #pragma unroll
        for (int r = 0; r < 4; r++) {
            int n = n0 + half * 16 + quad * 4 + r;
            float v = acc[r] + bo;
            if (z < 2) projf[(size_t)(b * 4096 + n) * 256 + o] = f2h(v);
            else       gT[(size_t)(b * 128 + (o - 256)) * 4096 + n] = f2b(v);
        }
    }
}

// ============================================================================
// Kernel 3: flash, S^T orientation. 512 thr, 8 waves x 4 strips (64 q/wave,
// q-tile 512), KQ-split. S^T = K.Q^T (A=K, B=Q): C-layout col=q, row=key ->
// thread holds 4 consecutive keys -> packed b64 Ps writes. PV: O^T = V.P^T
// (A=V frag, B=Ps rows contiguous b128). Fixed-shift softmax; l via ones-A
// MFMA. bf16 opart/oml partials (common scale, merged by plain sums in wy_k).
// ============================================================================
__global__ __launch_bounds__(512, 2) void flash_k(const ushort_t* __restrict__ projf,
                                                  const ushort_t* __restrict__ gT,
                                                  ushort_t* __restrict__ opart,
                                                  ushort_t* __restrict__ oml,
                                                  int kqlog) {
    __shared__ __align__(16) ushort_t KsF[2][8192];   // fp16 K, frag-order
    __shared__ __align__(16) ushort_t VsF[2][8192];   // bf16 V, frag-order
    __shared__ __align__(16) ushort_t Ps[512 * 72];   // bf16 [qrow][key], pad->72

    int b = blockIdx.y;
    int kq = blockIdx.x & ((1 << kqlog) - 1);
    int q0 = (blockIdx.x >> kqlog) * 512;
    int iters = 64 >> kqlog;
    int kt0 = kq * iters;
    int tid = threadIdx.x, w = tid >> 6, lane = tid & 63;
    int mrow = lane & 15, quad = lane >> 4, koff = quad * 8;

    int kRow[2], kCol[2], vIc[2], vOf[2], dstB[2];
    #pragma unroll
    for (int i = 0; i < 2; i++) {
        int ck = tid + i * 512, combo = ck >> 6, l2 = ck & 63;
        kRow[i] = (combo >> 2) * 16 + (l2 & 15);
        kCol[i] = 128 + (combo & 3) * 32 + (l2 >> 4) * 8;
        vIc[i]  = (combo >> 1) * 16 + (l2 & 15);
        vOf[i]  = (combo & 1) * 32 + (l2 >> 4) * 8;
        dstB[i] = (i * 512 + w * 64) * 8;
    }

    // Q B-frags: 4 strips x 16 q-rows (B[n=q=lane&15][k=ic=quad*8+j])
    half8 qf[4][4];
    #pragma unroll
    for (int s = 0; s < 4; s++)
        #pragma unroll
        for (int kk = 0; kk < 4; kk++)
            qf[s][kk] = *(const half8*)(projf + (size_t)(b * 4096 + q0 + w * 64 + s * 16 + mrow) * 256
                                        + kk * 32 + koff);

    float4v oacc[4][8], oaccL[4];
    #pragma unroll
    for (int s = 0; s < 4; s++) {
        oaccL[s] = (float4v){0.f, 0.f, 0.f, 0.f};
        #pragma unroll
        for (int ot = 0; ot < 8; ot++) oacc[s][ot] = (float4v){0.f, 0.f, 0.f, 0.f};
    }
    short8 vones;
    #pragma unroll
    for (int j = 0; j < 8; j++) vones[j] = (short)0x3F80;   // bf16 1.0

    {   // prologue: stage kt0 into buf 0
        int kb = kt0 * 64;
        #pragma unroll
        for (int i = 0; i < 2; i++) {
            glds16(projf + (size_t)(b * 4096 + kb + kRow[i]) * 256 + kCol[i], &KsF[0][dstB[i]]);
            glds16(gT + (size_t)(b * 128 + vIc[i]) * 4096 + kb + vOf[i], &VsF[0][dstB[i]]);
        }
    }

    for (int kt = kt0; kt < kt0 + iters; kt++) {
        int cur = (kt - kt0) & 1;
        __syncthreads();                              // publishes buf[cur]
        if (kt + 1 < kt0 + iters) {                   // prefetch next
            int kb = (kt + 1) * 64;
            #pragma unroll
            for (int i = 0; i < 2; i++) {
                glds16(projf + (size_t)(b * 4096 + kb + kRow[i]) * 256 + kCol[i], &KsF[1 - cur][dstB[i]]);
                glds16(gT + (size_t)(b * 128 + vIc[i]) * 4096 + kb + vOf[i], &VsF[1 - cur][dstB[i]]);
            }
        }

        // S^T per key-tile ct: A=K frag, B=Q regs; softmax + packed Ps write
        #pragma unroll
        for (int ct = 0; ct < 4; ct++) {
            float4v sc[4];
            #pragma unroll
            for (int s = 0; s < 4; s++) sc[s] = (float4v){0.f, 0.f, 0.f, 0.f};
            #pragma unroll
            for (int kk = 0; kk < 4; kk++) {
                half8 ak = *(const half8*)&KsF[cur][((ct * 4 + kk) * 64 + lane) * 8];
                #pragma unroll
                for (int s = 0; s < 4; s++)
                    sc[s] = __builtin_amdgcn_mfma_f32_16x16x32_f16(ak, qf[s][kk], sc[s], 0, 0, 0);
            }
            #pragma unroll
            for (int s = 0; s < 4; s++) {
                ushort4v pk;
                #pragma unroll
                for (int r = 0; r < 4; r++)
                    pk[r] = f2b(__builtin_exp2f(fmaf(sc[s][r], 1.44269504f, -92.332481f)));
                *(ushort4v*)&Ps[(w * 64 + s * 16 + mrow) * 72 + ct * 16 + quad * 4] = pk;
            }
        }
        __builtin_amdgcn_s_waitcnt(0xC07F);           // lgkmcnt(0): wave-private Ps

        // O^T += V.P^T : A=V frag (shared over strips), B=Ps row b128
        #pragma unroll
        for (int k2 = 0; k2 < 2; k2++) {
            short8 bq[4];
            #pragma unroll
            for (int s = 0; s < 4; s++)
                bq[s] = *(const short8*)&Ps[(w * 64 + s * 16 + mrow) * 72 + k2 * 32 + koff];
            #pragma unroll
            for (int ot = 0; ot < 8; ot++) {
                short8 av = *(const short8*)&VsF[cur][((ot * 2 + k2) * 64 + lane) * 8];
                #pragma unroll
                for (int s = 0; s < 4; s++)
                    oacc[s][ot] = __builtin_amdgcn_mfma_f32_16x16x32_bf16(av, bq[s], oacc[s][ot], 0, 0, 0);
            }
            #pragma unroll
            for (int s = 0; s < 4; s++)
                oaccL[s] = __builtin_amdgcn_mfma_f32_16x16x32_bf16(vones, bq[s], oaccL[s], 0, 0, 0);
        }
    }

    // epilogue: O^T C-layout (col=q=mrow, row=ic=ot*16+quad*4+r) -> packed
    #pragma unroll
    for (int s = 0; s < 4; s++) {
        int R = b * 4096 + q0 + w * 64 + s * 16 + mrow;
        #pragma unroll
        for (int ot = 0; ot < 8; ot++) {
            ushort4v ov;
            #pragma unroll
            for (int r = 0; r < 4; r++) ov[r] = f2b(oacc[s][ot][r]);
            *(ushort4v*)(opart + ((size_t)kq * 16384 + R) * 128 + ot * 16 + quad * 4) = ov;
        }
        if (quad == 0) oml[kq * 16384 + R] = f2b(oaccL[s][0]);
    }
}

// ============================================================================
// Kernel 4: wy = w_w . y2^T + w_b, inline merge of KQ bf16 partials
// (common scale -> plain sums), split-bf16 GEMM, fused per-channel stats.
// ============================================================================
__global__ __launch_bounds__(256) void wy_k(const ushort_t* __restrict__ opart,
                                            const ushort_t* __restrict__ oml,
                                            const ushort_t* __restrict__ wwbh,
                                            const ushort_t* __restrict__ wwbl,
                                            const float* __restrict__ w_b,
                                            ushort_t* __restrict__ wy,
                                            float* __restrict__ stats, int KQ) {
    __shared__ float s_sum[256], s_sq[256];
    int b = blockIdx.y, n0 = blockIdx.x * 32;
    int tid = threadIdx.x, w = tid >> 6, lane = tid & 63;
    s_sum[tid] = 0.f; s_sq[tid] = 0.f;
    __syncthreads();
    int mrow = lane & 15, quad = lane >> 4, koff = quad * 8;
    int half = w & 1, sect = w >> 1;
    int Rn = b * 4096 + n0 + half * 16 + mrow;

    float L = 0.f;
    for (int kq = 0; kq < KQ; kq++) L += b2f(oml[kq * 16384 + Rn]);
    float invL = 1.f / L;

    short8 bfh[4], bfl[4];
    #pragma unroll
    for (int kk = 0; kk < 4; kk++) {
        float a[8];
        #pragma unroll
        for (int j = 0; j < 8; j++) a[j] = 0.f;
        for (int kq = 0; kq < KQ; kq++) {
            ushort8 v = *(const ushort8*)(opart + ((size_t)kq * 16384 + Rn) * 128 + kk * 32 + koff);
            #pragma unroll
            for (int j = 0; j < 8; j++) a[j] += b2f(v[j]);
        }
        #pragma unroll
        for (int j = 0; j < 8; j++) {
            ushort_t h, l;
            split2(a[j] * invL, h, l);
            bfh[kk][j] = (short)h; bfl[kk][j] = (short)l;
        }
    }

    int coln = n0 + half * 16 + mrow;
    for (int cot = sect * 8; cot < sect * 8 + 8; cot++) {
        float4v acc = {0.f, 0.f, 0.f, 0.f};
        #pragma unroll
        for (int kk = 0; kk < 4; kk++) {
            size_t woff = (size_t)(cot * 16 + mrow) * 128 + kk * 32 + koff;
            short8 ah = *(const short8*)(wwbh + woff);
            short8 al = *(const short8*)(wwbl + woff);
            acc = __builtin_amdgcn_mfma_f32_16x16x32_bf16(ah, bfh[kk], acc, 0, 0, 0);
            acc = __builtin_amdgcn_mfma_f32_16x16x32_bf16(ah, bfl[kk], acc, 0, 0, 0);
            acc = __builtin_amdgcn_mfma_f32_16x16x32_bf16(al, bfh[kk], acc, 0, 0, 0);
        }
        #pragma unroll
        for (int r = 0; r < 4; r++) {
            int co = cot * 16 + quad * 4 + r;
            float v = acc[r] + w_b[co];
            wy[(size_t)(b * 256 + co) * 4096 + coln] = f2b(v);
            float sv = v, sq = v * v;
            #pragma unroll
            for (int d = 1; d < 16; d <<= 1) {
                sv += __shfl_xor(sv, d, 64);
                sq += __shfl_xor(sq, d, 64);
            }
            if (mrow == 0) { atomicAdd(&s_sum[co], sv); atomicAdd(&s_sq[co], sq); }
        }
    }
    __syncthreads();
    atomicAdd(&stats[tid], s_sum[tid]);
    atomicAdd(&stats[256 + tid], s_sq[tid]);
}

// ============================================================================
// Kernel 5: BN (batch stats, biased var, eps=1e-5) + residual, f32 out.
// ============================================================================
__global__ __launch_bounds__(256) void bn_k(const ushort_t* __restrict__ wy,
                                            const float* __restrict__ x,
                                            const float* __restrict__ gamma,
                                            const float* __restrict__ beta,
                                            const float* __restrict__ stats,
                                            float* __restrict__ out) {
    int idx = (blockIdx.x * 256 + threadIdx.x) * 8;     // B*C*N = 1<<22
    int c = (idx >> 12) & 255;
    const float inv_cnt = 1.f / 16384.f;
    float mean = stats[c] * inv_cnt;
    float var  = stats[256 + c] * inv_cnt - mean * mean;
    float inv  = rsqrtf(var + 1e-5f);
    float scale = gamma[c] * inv;
    float shift = beta[c] - mean * scale;
    ushort8 wv = *(const ushort8*)(wy + idx);
    float4v x0 = *(const float4v*)(x + idx);
    float4v x1 = *(const float4v*)(x + idx + 4);
    float4v o0, o1;
    #pragma unroll
    for (int j = 0; j < 4; j++) {
        o0[j] = b2f(wv[j]) * scale + shift + x0[j];
        o1[j] = b2f(wv[4 + j]) * scale + shift + x1[j];
    }
    *(float4v*)(out + idx) = o0;
    *(float4v*)(out + idx + 4) = o1;
}

extern "C" void kernel_launch(void* const* d_in, const int* in_sizes, int n_in,
                              void* d_out, int out_size, void* d_ws, size_t ws_size,
                              hipStream_t stream) {
    const float* x    = (const float*)d_in[0];
    const float* y    = (const float*)d_in[1];
    const float* g_w  = (const float*)d_in[2];
    const float* g_b  = (const float*)d_in[3];
    const float* dx_w = (const float*)d_in[4];
    const float* dx_b = (const float*)d_in[5];
    const float* dy_w = (const float*)d_in[6];
    const float* dy_b = (const float*)d_in[7];
    const float* w_w  = (const float*)d_in[8];
    const float* w_b  = (const float*)d_in[9];
    const float* bn_g = (const float*)d_in[10];
    const float* bn_b = (const float*)d_in[11];

    char* ws = (char*)d_ws;
    ushort_t* wtf   = (ushort_t*)(ws + WTF_OFF);
    ushort_t* wwbh  = (ushort_t*)(ws + WWBH_OFF);
    ushort_t* wwbl  = (ushort_t*)(ws + WWBL_OFF);
    float*    bias  = (float*)(ws + BIAS_OFF);
    float*    stats = (float*)(ws + STATS_OFF);
    ushort_t* projf = (ushort_t*)(ws + PROJF_OFF);
    ushort_t* gT    = (ushort_t*)(ws + GT_OFF);
    ushort_t* opart = (ushort_t*)(ws + OPART_OFF);
    ushort_t* wy    = (ushort_t*)(ws + WY_OFF);   // reuses projf region
    float*    out   = (float*)d_out;

    // ws-adaptive K-split (bf16 partials): KQ=8 -> 256 blocks of q-tile 512.
    int kqlog;
    if      (ws_size >= 12976128u + 8u * (4194304u + 32768u)) kqlog = 3;
    else if (ws_size >= 12976128u + 4u * (4194304u + 32768u)) kqlog = 2;
    else                                                      kqlog = 1;
    int KQ = 1 << kqlog;
    ushort_t* oml = opart + (size_t)KQ * 2097152u;   // element offset (4 MB/kq)

    prep_k<<<384, 256, 0, stream>>>(dx_w, dy_w, g_w, dx_b, dy_b, g_b, w_w,
                                    wtf, wwbh, wwbl, bias, stats);
    proj_k<<<dim3(128, 4, 3), 256, 0, stream>>>(x, y, wtf, bias, projf, gT);
    flash_k<<<dim3(8 << kqlog, 4), 512, 0, stream>>>(projf, gT, opart, oml, kqlog);
    wy_k<<<dim3(128, 4), 256, 0, stream>>>(opart, oml, wwbh, wwbl, w_b, wy, stats, KQ);
    bn_k<<<2048, 256, 0, stream>>>(wy, x, bn_g, bn_b, stats, out);
}